// Round 6
// baseline (1617.477 us; speedup 1.0000x reference)
//
#include <hip/hip_runtime.h>
#include <stdint.h>
#include <stddef.h>

// VectorQuantization — N=32768, K=8192, D=256 fp32 -> int32 argmin.
// Round 6: barrier-free K-loop (flatmm-style). Round 5 regressed from (a)
// register spills at launch_bounds(256,4) (WRITE_SIZE 1MB->417MB) and (b) a
// broken bank swizzle (fr&3 XOR left fr&1 in the bank phase -> 4-way).
// Round 4 was the m97 barrier-drain plateau (MfmaUtil 48%).
// New structure:
//   - A slab (128 points, full D, xh+xl f16) staged ONCE per block into
//     128KB LDS via global_load_lds w=16, XOR swizzle granule^=(row&7)
//     (full 3-bit XOR -> 2-way conflicts = free). ONE barrier per block.
//   - B (codes, ch+cl) streamed from L2 directly into VGPRs inside the
//     kt x dk loop — NO __syncthreads in the hot loop; compiler manages
//     fine-grained vmcnt on register loads (the AITER pattern).
//   - 512-thread blocks (8 waves 2x4), 1 block/CU, grid 1024 = 4 clean
//     generations. SPLITK=4: split=blk&3, XCD=blk%8 -> 2MB B-chunk per XCD L2.
// Numerics (validated rounds 3-5, absmax 0):
//   x.c = xh*ch + (xh*2^-11)*(cl*2^11) + (xl*2^11)*(ch*2^-11)
//   argmin_k(c2[k] - 2*x.c); strict-< ascending scan + lex (val,idx) merges
//   == np.argmin first-min tie rule.

#define N_PTS 32768
#define K_CB  8192
#define D_DIM 256
#define TM 128
#define TN 128
#define SPLITK 4
#define KCHUNK (K_CB / SPLITK)   // 2048
#define NTILES (KCHUNK / TN)     // 16
#define ROWB   (D_DIM * 2)       // 512 bytes per f16 row

// ws layout (byte offsets; all 16B-aligned) — same as rounds 4/5 (43MB, fits)
#define WS_XH   0
#define WS_XL   (WS_XH + N_PTS * D_DIM * 2)
#define WS_CH   (WS_XL + N_PTS * D_DIM * 2)
#define WS_CL   (WS_CH + K_CB * D_DIM * 2)
#define WS_C2   (WS_CL + K_CB * D_DIM * 2)
#define WS_PD   (WS_C2 + K_CB * 4)
#define WS_PI   (WS_PD + SPLITK * N_PTS * 4)
#define WS_END  (WS_PI + SPLITK * N_PTS * 4)

typedef _Float16 half4v __attribute__((ext_vector_type(4)));
typedef _Float16 half8v __attribute__((ext_vector_type(8)));
typedef float    f32x4  __attribute__((ext_vector_type(4)));

__device__ __forceinline__ void gld16(const void* g, void* l) {
    __builtin_amdgcn_global_load_lds(
        (const __attribute__((address_space(1))) void*)g,
        (__attribute__((address_space(3))) void*)l, 16, 0, 0);
}

// ---------------- preprocessing ----------------

__global__ void __launch_bounds__(256)
split_kernel(const float* __restrict__ src, _Float16* __restrict__ h_out,
             _Float16* __restrict__ l_out) {
    const int i = blockIdx.x * 256 + threadIdx.x;   // one float4 per thread
    const float4 v = ((const float4*)src)[i];
    half4v h = {(_Float16)v.x, (_Float16)v.y, (_Float16)v.z, (_Float16)v.w};
    half4v l = {(_Float16)((v.x - (float)h[0]) * 2048.0f),
                (_Float16)((v.y - (float)h[1]) * 2048.0f),
                (_Float16)((v.z - (float)h[2]) * 2048.0f),
                (_Float16)((v.w - (float)h[3]) * 2048.0f)};
    *(half4v*)(h_out + (size_t)i * 4) = h;
    *(half4v*)(l_out + (size_t)i * 4) = l;
}

// codebook: split + norm fused, one wave per row
__global__ void __launch_bounds__(256)
csplit_norm(const float* __restrict__ vecs, _Float16* __restrict__ h_out,
            _Float16* __restrict__ l_out, float* __restrict__ c2) {
    const int row  = (blockIdx.x * 256 + threadIdx.x) >> 6;
    const int lane = threadIdx.x & 63;
    const float4 v = ((const float4*)(vecs + (size_t)row * D_DIM))[lane];
    half4v h = {(_Float16)v.x, (_Float16)v.y, (_Float16)v.z, (_Float16)v.w};
    half4v l = {(_Float16)((v.x - (float)h[0]) * 2048.0f),
                (_Float16)((v.y - (float)h[1]) * 2048.0f),
                (_Float16)((v.z - (float)h[2]) * 2048.0f),
                (_Float16)((v.w - (float)h[3]) * 2048.0f)};
    *(half4v*)(h_out + (size_t)row * D_DIM + lane * 4) = h;
    *(half4v*)(l_out + (size_t)row * D_DIM + lane * 4) = l;
    float s = v.x * v.x + v.y * v.y + v.z * v.z + v.w * v.w;
#pragma unroll
    for (int off = 32; off > 0; off >>= 1) s += __shfl_down(s, off, 64);
    if (lane == 0) c2[row] = s;
}

// ---------------- main kernel ----------------

__global__ void __launch_bounds__(512, 2)
vq_main_fast(const _Float16* __restrict__ xh_g, const _Float16* __restrict__ xl_g,
             const _Float16* __restrict__ ch_g, const _Float16* __restrict__ cl_g,
             const float* __restrict__ c2, float* __restrict__ pd, int* __restrict__ pi) {
    // xh [0,64K), xl [64K,128K); row = 512B, 32 granules of 16B, phys granule
    // p of row r holds logical granule p ^ (r&7).
    __shared__ __align__(16) char lds[131072];

    const int t    = threadIdx.x;
    const int lane = t & 63;
    const int wv   = t >> 6;                 // 8 waves
    const int wy   = wv >> 2, wx = wv & 3;   // 2x4 over 128x128
    const int fr   = lane & 15;              // row/col within 16x16 tile
    const int g    = lane >> 4;              // k-group 0..3

    const int split = blockIdx.x & (SPLITK - 1);
    const int pbase = (blockIdx.x >> 2) * TM;
    const int kbase = split * KCHUNK;

    // ---- one-time A staging (xh, xl full-D) ----
    {
        const int p31 = lane & 31, rhalf = lane >> 5;   // 2 rows per gld16
#pragma unroll
        for (int q = 0; q < 8; ++q) {
            const int row = wv * 16 + q * 2 + rhalf;
            const int l   = p31 ^ (row & 7);            // swizzled source granule
            const size_t go = (size_t)(pbase + row) * ROWB + l * 16;
            gld16((const char*)xh_g + go, lds +         (wv * 16 + q * 2) * ROWB);
            gld16((const char*)xl_g + go, lds + 65536 + (wv * 16 + q * 2) * ROWB);
        }
    }
    __syncthreads();   // the only barrier before the epilogue

    const int fr7 = fr & 7;   // == (A-row & 7) for this lane's fragment rows
    int abase[4];
#pragma unroll
    for (int i = 0; i < 4; ++i) abase[i] = (wy * 64 + i * 16 + fr) * ROWB;

    float best[16];
    int   bidx[16];
#pragma unroll
    for (int i = 0; i < 16; ++i) { best[i] = 3.4e38f; bidx[i] = 0; }

    for (int kt = 0; kt < NTILES; ++kt) {
        const int ktbase = kbase + kt * TN;
        const char* bh[2];
        const char* bl[2];
#pragma unroll
        for (int j = 0; j < 2; ++j) {
            const size_t ro = (size_t)(ktbase + wx * 32 + j * 16 + fr) * ROWB + g * 16;
            bh[j] = (const char*)ch_g + ro;
            bl[j] = (const char*)cl_g + ro;
        }

        f32x4 acc[4][2];
#pragma unroll
        for (int i = 0; i < 4; ++i)
#pragma unroll
            for (int j = 0; j < 2; ++j) {
                f32x4 z = {0.f, 0.f, 0.f, 0.f};
                acc[i][j] = z;
            }

#pragma unroll
        for (int dk = 0; dk < 8; ++dk) {          // 8 k-steps of K=32 halves
            half8v b1[2], b2[2];
#pragma unroll
            for (int j = 0; j < 2; ++j) {         // B straight from L2 (no LDS)
                b1[j] = *(const half8v*)(bh[j] + dk * 64);
                b2[j] = *(const half8v*)(bl[j] + dk * 64);
            }
            const int go = ((dk * 4 + g) ^ fr7) << 4;   // swizzled A granule
            half8v a1[4], a2[4], a3[4];
#pragma unroll
            for (int i = 0; i < 4; ++i) {
                a1[i] = *(const half8v*)(lds + abase[i] + go);           // xh
                a3[i] = *(const half8v*)(lds + 65536 + abase[i] + go);   // xl*2^11
                a2[i] = a1[i] * (_Float16)4.8828125e-4f;                 // xh*2^-11
            }
#pragma unroll
            for (int j = 0; j < 2; ++j) {
                const half8v b3 = b1[j] * (_Float16)4.8828125e-4f;       // ch*2^-11
#pragma unroll
                for (int i = 0; i < 4; ++i) {
                    acc[i][j] = __builtin_amdgcn_mfma_f32_16x16x32_f16(a1[i], b1[j], acc[i][j], 0, 0, 0);
                    acc[i][j] = __builtin_amdgcn_mfma_f32_16x16x32_f16(a2[i], b2[j], acc[i][j], 0, 0, 0);
                    acc[i][j] = __builtin_amdgcn_mfma_f32_16x16x32_f16(a3[i], b3,    acc[i][j], 0, 0, 0);
                }
            }
        }

        // merge tile into running argmin; ascending j + strict < == np first-min
#pragma unroll
        for (int j = 0; j < 2; ++j) {
            const int cg = ktbase + wx * 32 + j * 16 + fr;
            const float c2v = c2[cg];
#pragma unroll
            for (int i = 0; i < 4; ++i)
#pragma unroll
                for (int r = 0; r < 4; ++r) {
                    const float v = fmaf(-2.0f, acc[i][j][r], c2v);
                    const int s = i * 4 + r;
                    if (v < best[s]) { best[s] = v; bidx[s] = cg; }
                }
        }
    }

    // reduce across the 16 fr-lanes per point row, then the 4 wx wave-columns
    __syncthreads();   // all waves done reading A before LDS reuse
    float* rd = (float*)lds;          // 128 rows x 4 cols
    int*   ri = (int*)lds + 512;
#pragma unroll
    for (int i = 0; i < 4; ++i)
#pragma unroll
        for (int r = 0; r < 4; ++r) {
            float bv = best[i * 4 + r];
            int   bi = bidx[i * 4 + r];
#pragma unroll
            for (int off = 1; off < 16; off <<= 1) {
                const float ov = __shfl_xor(bv, off, 64);
                const int   oi = __shfl_xor(bi, off, 64);
                if (ov < bv || (ov == bv && oi < bi)) { bv = ov; bi = oi; }
            }
            if (fr == 0) {
                const int rowl = wy * 64 + i * 16 + g * 4 + r;
                rd[rowl * 4 + wx] = bv;
                ri[rowl * 4 + wx] = bi;
            }
        }
    __syncthreads();
    if (t < TM) {
        float b0 = rd[t * 4];
        int   i0 = ri[t * 4];
#pragma unroll
        for (int c = 1; c < 4; ++c) {
            const float v  = rd[t * 4 + c];
            const int   vi = ri[t * 4 + c];
            if (v < b0 || (v == b0 && vi < i0)) { b0 = v; i0 = vi; }
        }
        pd[split * N_PTS + pbase + t] = b0;
        pi[split * N_PTS + pbase + t] = i0;
    }
}

// ---------------- combine ----------------

__global__ void __launch_bounds__(256)
vq_combine(const float* __restrict__ pd, const int* __restrict__ pi,
           int* __restrict__ out) {
    const int p = blockIdx.x * 256 + threadIdx.x;
    float bb = pd[p];
    int   bi = pi[p];
#pragma unroll
    for (int s = 1; s < SPLITK; ++s) {
        const float v  = pd[s * N_PTS + p];
        const int   vi = pi[s * N_PTS + p];
        if (v < bb || (v == bb && vi < bi)) { bb = v; bi = vi; }
    }
    out[p] = bi;
}

extern "C" void kernel_launch(void* const* d_in, const int* in_sizes, int n_in,
                              void* d_out, int out_size, void* d_ws, size_t ws_size,
                              hipStream_t stream) {
    const float* x    = (const float*)d_in[0];
    const float* vecs = (const float*)d_in[1];
    int* out = (int*)d_out;
    char* ws = (char*)d_ws;
    // ws_size >= 43MB verified empirically (rounds 4/5 ran this layout).

    _Float16* xh = (_Float16*)(ws + WS_XH);
    _Float16* xl = (_Float16*)(ws + WS_XL);
    _Float16* ch = (_Float16*)(ws + WS_CH);
    _Float16* cl = (_Float16*)(ws + WS_CL);
    float* c2 = (float*)(ws + WS_C2);
    float* pd = (float*)(ws + WS_PD);
    int*   pi = (int*)(ws + WS_PI);

    hipLaunchKernelGGL(split_kernel, dim3(N_PTS * D_DIM / 4 / 256), dim3(256), 0, stream,
                       x, xh, xl);
    hipLaunchKernelGGL(csplit_norm, dim3(K_CB / 4), dim3(256), 0, stream,
                       vecs, ch, cl, c2);
    hipLaunchKernelGGL(vq_main_fast, dim3((N_PTS / TM) * SPLITK), dim3(512), 0, stream,
                       xh, xl, ch, cl, c2, pd, pi);
    hipLaunchKernelGGL(vq_combine, dim3(N_PTS / 256), dim3(256), 0, stream,
                       pd, pi, out);
}

// Round 7
// 1190.372 us; speedup vs baseline: 1.3588x; 1.3588x over previous
//
#include <hip/hip_runtime.h>
#include <stdint.h>
#include <stddef.h>

// VectorQuantization — N=32768, K=8192, D=256 fp32 -> int32 argmin.
// Round 7 = round 6's barrier-free structure with the two memory bugs fixed:
//   (a) NO VGPR cap: __launch_bounds__(512) bare. 128KB LDS forces 1 block/CU
//       (8 waves, 2/SIMD); need ~170 VGPR < 256 hard limit -> no spills.
//       (Rounds 5/6 proved: min-waves arg capping VGPR<180 => 400-500MB scratch.)
//   (b) B pre-packed in MFMA fragment order (16-row groups, k-slot major):
//       every B load is base + dk*1024 + lane*16 -> perfectly coalesced 1KB
//       global_load_dwordx4 straight from L2 (per-XCD 2MB chunk), no LDS, no
//       barriers in the hot loop.
//   (c) two-accumulator split (no in-loop operand derivation, no f16 denorms):
//       acc_h += xh*ch ; acc_m += xh*cl2 + xl2*ch   (cl2 = resid*2^11)
//       d2 = c2 - 2*acc_h - 2^-10*acc_m
// A slab (128 points, full D, xh+xl) staged ONCE per block into 128KB LDS via
// global_load_lds w=16 with the validated granule^=(row&7) XOR swizzle; one
// barrier per block. SPLITK=4: split=blk&3, XCD=blk%8 -> one 2MB B chunk per
// XCD L2. Strict-< ascending scan + lex (val,idx) merges == np.argmin
// first-min tie rule (validated rounds 3-6, absmax 0).

#define N_PTS 32768
#define K_CB  8192
#define D_DIM 256
#define TM 128
#define TN 128
#define SPLITK 4
#define KCHUNK (K_CB / SPLITK)   // 2048
#define NTILES (KCHUNK / TN)     // 16
#define ROWB   (D_DIM * 2)       // 512 bytes per f16 row

// ws layout (byte offsets; all 16B-aligned) — 43MB, fits (ran rounds 4-6)
#define WS_XH   0
#define WS_XL   (WS_XH + N_PTS * D_DIM * 2)
#define WS_CH   (WS_XL + N_PTS * D_DIM * 2)   // packed
#define WS_CL   (WS_CH + K_CB * D_DIM * 2)    // packed
#define WS_C2   (WS_CL + K_CB * D_DIM * 2)
#define WS_PD   (WS_C2 + K_CB * 4)
#define WS_PI   (WS_PD + SPLITK * N_PTS * 4)
#define WS_END  (WS_PI + SPLITK * N_PTS * 4)

typedef _Float16 half4v __attribute__((ext_vector_type(4)));
typedef _Float16 half8v __attribute__((ext_vector_type(8)));
typedef float    f32x4  __attribute__((ext_vector_type(4)));

__device__ __forceinline__ void gld16(const void* g, void* l) {
    __builtin_amdgcn_global_load_lds(
        (const __attribute__((address_space(1))) void*)g,
        (__attribute__((address_space(3))) void*)l, 16, 0, 0);
}

// ---------------- preprocessing ----------------

// x: row-major split (feeds the A slab DMA)
__global__ void __launch_bounds__(256)
split_kernel(const float* __restrict__ src, _Float16* __restrict__ h_out,
             _Float16* __restrict__ l_out) {
    const int i = blockIdx.x * 256 + threadIdx.x;   // one float4 per thread
    const float4 v = ((const float4*)src)[i];
    half4v h = {(_Float16)v.x, (_Float16)v.y, (_Float16)v.z, (_Float16)v.w};
    half4v l = {(_Float16)((v.x - (float)h[0]) * 2048.0f),
                (_Float16)((v.y - (float)h[1]) * 2048.0f),
                (_Float16)((v.z - (float)h[2]) * 2048.0f),
                (_Float16)((v.w - (float)h[3]) * 2048.0f)};
    *(half4v*)(h_out + (size_t)i * 4) = h;
    *(half4v*)(l_out + (size_t)i * 4) = l;
}

// codebook: split + fragment-order pack + norm, one wave per code row.
// pack layout (halves): ((group*32 + kslot)*16 + r)*8 + sub
//   group=row/16, r=row%16, kslot=k/8, sub=k%8
// -> main-kernel load for (dk,lane) is jg*4096 + dk*512 + lane*8 (coalesced).
__global__ void __launch_bounds__(256)
cpack_norm(const float* __restrict__ vecs, _Float16* __restrict__ ph,
           _Float16* __restrict__ pl, float* __restrict__ c2) {
    const int row  = (blockIdx.x * 256 + threadIdx.x) >> 6;
    const int lane = threadIdx.x & 63;
    const float4 v = ((const float4*)(vecs + (size_t)row * D_DIM))[lane];
    half4v h = {(_Float16)v.x, (_Float16)v.y, (_Float16)v.z, (_Float16)v.w};
    half4v l = {(_Float16)((v.x - (float)h[0]) * 2048.0f),
                (_Float16)((v.y - (float)h[1]) * 2048.0f),
                (_Float16)((v.z - (float)h[2]) * 2048.0f),
                (_Float16)((v.w - (float)h[3]) * 2048.0f)};
    const int group = row >> 4, r = row & 15;
    const size_t di = ((size_t)(group * 32 + (lane >> 1)) * 16 + r) * 8 + (lane & 1) * 4;
    *(half4v*)(ph + di) = h;
    *(half4v*)(pl + di) = l;
    float s = v.x * v.x + v.y * v.y + v.z * v.z + v.w * v.w;
#pragma unroll
    for (int off = 32; off > 0; off >>= 1) s += __shfl_down(s, off, 64);
    if (lane == 0) c2[row] = s;
}

// ---------------- main kernel ----------------

__global__ void __launch_bounds__(512)
vq_main_fast(const _Float16* __restrict__ xh_g, const _Float16* __restrict__ xl_g,
             const _Float16* __restrict__ ch_p, const _Float16* __restrict__ cl_p,
             const float* __restrict__ c2, float* __restrict__ pd, int* __restrict__ pi) {
    // xh [0,64K), xl [64K,128K); row = 512B = 32 granules of 16B; phys granule
    // p of row r holds logical granule p ^ (r&7).
    __shared__ __align__(16) char lds[131072];

    const int t    = threadIdx.x;
    const int lane = t & 63;
    const int wv   = t >> 6;                 // 8 waves
    const int wy   = wv >> 2, wx = wv & 3;   // 2x4 over 128x128
    const int fr   = lane & 15;              // row/col within 16x16 tile
    const int g    = lane >> 4;              // k-group 0..3

    const int split = blockIdx.x & (SPLITK - 1);
    const int pbase = (blockIdx.x >> 2) * TM;
    const int kbase = split * KCHUNK;

    // ---- one-time A staging (xh, xl full-D), validated in round 6 ----
    {
        const int p31 = lane & 31, rhalf = lane >> 5;   // 2 rows per gld16
#pragma unroll
        for (int q = 0; q < 8; ++q) {
            const int row = wv * 16 + q * 2 + rhalf;
            const int lg  = p31 ^ (row & 7);            // swizzled source granule
            const size_t go = (size_t)(pbase + row) * ROWB + lg * 16;
            gld16((const char*)xh_g + go, lds +         (wv * 16 + q * 2) * ROWB);
            gld16((const char*)xl_g + go, lds + 65536 + (wv * 16 + q * 2) * ROWB);
        }
    }
    __syncthreads();   // the only barrier before the epilogue

    const int fr7 = fr & 7;
    int abase[4];
#pragma unroll
    for (int i = 0; i < 4; ++i) abase[i] = (wy * 64 + i * 16 + fr) * ROWB;

    float best[16];
    int   bidx[16];
#pragma unroll
    for (int i = 0; i < 16; ++i) { best[i] = 3.4e38f; bidx[i] = 0; }

    for (int kt = 0; kt < NTILES; ++kt) {
        const int ktbase = kbase + kt * TN;
        // packed-B slab bases: jg = 16-row group index; per-lane +lane*16
        const char* bh[2];
        const char* bl[2];
#pragma unroll
        for (int j = 0; j < 2; ++j) {
            const size_t jg = (size_t)((ktbase >> 4) + wx * 2 + j);
            bh[j] = (const char*)ch_p + jg * 8192 + lane * 16;
            bl[j] = (const char*)cl_p + jg * 8192 + lane * 16;
        }

        f32x4 acch[4][2], accm[4][2];
#pragma unroll
        for (int i = 0; i < 4; ++i)
#pragma unroll
            for (int j = 0; j < 2; ++j) {
                f32x4 z = {0.f, 0.f, 0.f, 0.f};
                acch[i][j] = z; accm[i][j] = z;
            }

#pragma unroll
        for (int dk = 0; dk < 8; ++dk) {          // 8 k-steps of 32 halves
            half8v b1[2], b2[2];
#pragma unroll
            for (int j = 0; j < 2; ++j) {         // coalesced 1KB loads from L2
                b1[j] = *(const half8v*)(bh[j] + dk * 1024);
                b2[j] = *(const half8v*)(bl[j] + dk * 1024);
            }
            const int go = ((dk * 4 + g) ^ fr7) << 4;   // swizzled A granule
            half8v a1[4], a3[4];
#pragma unroll
            for (int i = 0; i < 4; ++i) {
                a1[i] = *(const half8v*)(lds + abase[i] + go);           // xh
                a3[i] = *(const half8v*)(lds + 65536 + abase[i] + go);   // xl*2^11
            }
#pragma unroll
            for (int j = 0; j < 2; ++j)
#pragma unroll
                for (int i = 0; i < 4; ++i) {
                    acch[i][j] = __builtin_amdgcn_mfma_f32_16x16x32_f16(a1[i], b1[j], acch[i][j], 0, 0, 0);
                    accm[i][j] = __builtin_amdgcn_mfma_f32_16x16x32_f16(a1[i], b2[j], accm[i][j], 0, 0, 0);
                    accm[i][j] = __builtin_amdgcn_mfma_f32_16x16x32_f16(a3[i], b1[j], accm[i][j], 0, 0, 0);
                }
        }

        // merge tile into running argmin; ascending j + strict < == np first-min
        // d2 = c2 - 2*acc_h - 2^-10*acc_m   (2^-10 = 2 * 2^-11)
#pragma unroll
        for (int j = 0; j < 2; ++j) {
            const int cg = ktbase + wx * 32 + j * 16 + fr;
            const float c2v = c2[cg];
#pragma unroll
            for (int i = 0; i < 4; ++i)
#pragma unroll
                for (int r = 0; r < 4; ++r) {
                    const float v = fmaf(-2.0f, acch[i][j][r],
                                    fmaf(-9.765625e-4f, accm[i][j][r], c2v));
                    const int s = i * 4 + r;
                    if (v < best[s]) { best[s] = v; bidx[s] = cg; }
                }
        }
    }

    // reduce across the 16 fr-lanes per point row, then the 4 wx wave-columns
    __syncthreads();   // all waves done reading A before LDS reuse
    float* rd = (float*)lds;          // 128 rows x 4 cols
    int*   ri = (int*)lds + 512;
#pragma unroll
    for (int i = 0; i < 4; ++i)
#pragma unroll
        for (int r = 0; r < 4; ++r) {
            float bv = best[i * 4 + r];
            int   bi = bidx[i * 4 + r];
#pragma unroll
            for (int off = 1; off < 16; off <<= 1) {
                const float ov = __shfl_xor(bv, off, 64);
                const int   oi = __shfl_xor(bi, off, 64);
                if (ov < bv || (ov == bv && oi < bi)) { bv = ov; bi = oi; }
            }
            if (fr == 0) {
                const int rowl = wy * 64 + i * 16 + g * 4 + r;
                rd[rowl * 4 + wx] = bv;
                ri[rowl * 4 + wx] = bi;
            }
        }
    __syncthreads();
    if (t < TM) {
        float b0 = rd[t * 4];
        int   i0 = ri[t * 4];
#pragma unroll
        for (int c = 1; c < 4; ++c) {
            const float v  = rd[t * 4 + c];
            const int   vi = ri[t * 4 + c];
            if (v < b0 || (v == b0 && vi < i0)) { b0 = v; i0 = vi; }
        }
        pd[split * N_PTS + pbase + t] = b0;
        pi[split * N_PTS + pbase + t] = i0;
    }
}

// ---------------- combine ----------------

__global__ void __launch_bounds__(256)
vq_combine(const float* __restrict__ pd, const int* __restrict__ pi,
           int* __restrict__ out) {
    const int p = blockIdx.x * 256 + threadIdx.x;
    float bb = pd[p];
    int   bi = pi[p];
#pragma unroll
    for (int s = 1; s < SPLITK; ++s) {
        const float v  = pd[s * N_PTS + p];
        const int   vi = pi[s * N_PTS + p];
        if (v < bb || (v == bb && vi < bi)) { bb = v; bi = vi; }
    }
    out[p] = bi;
}

extern "C" void kernel_launch(void* const* d_in, const int* in_sizes, int n_in,
                              void* d_out, int out_size, void* d_ws, size_t ws_size,
                              hipStream_t stream) {
    const float* x    = (const float*)d_in[0];
    const float* vecs = (const float*)d_in[1];
    int* out = (int*)d_out;
    char* ws = (char*)d_ws;

    _Float16* xh = (_Float16*)(ws + WS_XH);
    _Float16* xl = (_Float16*)(ws + WS_XL);
    _Float16* ch = (_Float16*)(ws + WS_CH);
    _Float16* cl = (_Float16*)(ws + WS_CL);
    float* c2 = (float*)(ws + WS_C2);
    float* pd = (float*)(ws + WS_PD);
    int*   pi = (int*)(ws + WS_PI);

    hipLaunchKernelGGL(split_kernel, dim3(N_PTS * D_DIM / 4 / 256), dim3(256), 0, stream,
                       x, xh, xl);
    hipLaunchKernelGGL(cpack_norm, dim3(K_CB / 4), dim3(256), 0, stream,
                       vecs, ch, cl, c2);
    hipLaunchKernelGGL(vq_main_fast, dim3((N_PTS / TM) * SPLITK), dim3(512), 0, stream,
                       xh, xl, ch, cl, c2, pd, pi);
    hipLaunchKernelGGL(vq_combine, dim3(N_PTS / 256), dim3(256), 0, stream,
                       pd, pi, out);
}

// Round 8
// 853.441 us; speedup vs baseline: 1.8952x; 1.3948x over previous
//
#include <hip/hip_runtime.h>
#include <stdint.h>
#include <stddef.h>

// VectorQuantization — N=32768, K=8192, D=256 fp32 -> int32 argmin.
// Round 8 = round 7's barrier-free structure, reshaped to fit the 128-arch-VGPR
// cap the compiler imposes on 512-thread blocks (rounds 5-7: any spill =>
// 400-750MB scratch + L2 pollution = disaster).
//   Wave layout 4x2 (wave tile 32 rows x 64 cols, I=2 J=4):
//     a-frags 16 regs, b-frags 32, best/bidx 16, addr ~20 => ~100 arch VGPR;
//     64 accumulator regs go to AGPRs (round 4 precedent: 88 arch + acc AGPR).
//   A slab (128 points, full D, xh+xl) staged once into 128KB LDS via
//   global_load_lds w=16, granule^=(row&7) swizzle (validated: 2e6 conflicts).
//   B pre-packed in MFMA fragment order; loads = base + dk*1024 + lane*16,
//   coalesced 1KB from L2 (2MB chunk per XCD), no LDS, no hot-loop barriers.
//   Numerics (validated r3-r7, absmax 0): two-accumulator split-f16:
//     acc_h += xh*ch ; acc_m += xh*cl2 + xl2*ch  (l2 = resid*2^11)
//     d2 = c2 - 2*acc_h - 2^-10*acc_m
//   argmin: strict-< ascending (kt, then j) scan + lex (val,idx) reductions
//   == np.argmin first-min tie rule. SPLITK=4: split=blk&3, XCD=blk%8.

#define N_PTS 32768
#define K_CB  8192
#define D_DIM 256
#define TM 128
#define TN 128
#define SPLITK 4
#define KCHUNK (K_CB / SPLITK)   // 2048
#define NTILES (KCHUNK / TN)     // 16
#define ROWB   (D_DIM * 2)       // 512 bytes per f16 row

// ws layout (byte offsets; all 16B-aligned) — 43MB total
#define WS_XH   0
#define WS_XL   (WS_XH + N_PTS * D_DIM * 2)
#define WS_CH   (WS_XL + N_PTS * D_DIM * 2)   // packed
#define WS_CL   (WS_CH + K_CB * D_DIM * 2)    // packed
#define WS_C2   (WS_CL + K_CB * D_DIM * 2)
#define WS_PD   (WS_C2 + K_CB * 4)
#define WS_PI   (WS_PD + SPLITK * N_PTS * 4)
#define WS_END  (WS_PI + SPLITK * N_PTS * 4)

typedef _Float16 half4v __attribute__((ext_vector_type(4)));
typedef _Float16 half8v __attribute__((ext_vector_type(8)));
typedef float    f32x4  __attribute__((ext_vector_type(4)));

__device__ __forceinline__ void gld16(const void* g, void* l) {
    __builtin_amdgcn_global_load_lds(
        (const __attribute__((address_space(1))) void*)g,
        (__attribute__((address_space(3))) void*)l, 16, 0, 0);
}

// ---------------- preprocessing ----------------

// x: row-major split (feeds the A slab DMA)
__global__ void __launch_bounds__(256)
split_kernel(const float* __restrict__ src, _Float16* __restrict__ h_out,
             _Float16* __restrict__ l_out) {
    const int i = blockIdx.x * 256 + threadIdx.x;   // one float4 per thread
    const float4 v = ((const float4*)src)[i];
    half4v h = {(_Float16)v.x, (_Float16)v.y, (_Float16)v.z, (_Float16)v.w};
    half4v l = {(_Float16)((v.x - (float)h[0]) * 2048.0f),
                (_Float16)((v.y - (float)h[1]) * 2048.0f),
                (_Float16)((v.z - (float)h[2]) * 2048.0f),
                (_Float16)((v.w - (float)h[3]) * 2048.0f)};
    *(half4v*)(h_out + (size_t)i * 4) = h;
    *(half4v*)(l_out + (size_t)i * 4) = l;
}

// codebook: split + fragment-order pack + norm, one wave per code row.
// pack layout (halves): ((group*32 + kslot)*16 + r)*8 + sub
//   group=row/16, r=row%16, kslot=k/8, sub=k%8
// -> main-kernel load for (dk,lane) = jg*8192B + dk*1024B + lane*16B.
__global__ void __launch_bounds__(256)
cpack_norm(const float* __restrict__ vecs, _Float16* __restrict__ ph,
           _Float16* __restrict__ pl, float* __restrict__ c2) {
    const int row  = (blockIdx.x * 256 + threadIdx.x) >> 6;
    const int lane = threadIdx.x & 63;
    const float4 v = ((const float4*)(vecs + (size_t)row * D_DIM))[lane];
    half4v h = {(_Float16)v.x, (_Float16)v.y, (_Float16)v.z, (_Float16)v.w};
    half4v l = {(_Float16)((v.x - (float)h[0]) * 2048.0f),
                (_Float16)((v.y - (float)h[1]) * 2048.0f),
                (_Float16)((v.z - (float)h[2]) * 2048.0f),
                (_Float16)((v.w - (float)h[3]) * 2048.0f)};
    const int group = row >> 4, r = row & 15;
    const size_t di = ((size_t)(group * 32 + (lane >> 1)) * 16 + r) * 8 + (lane & 1) * 4;
    *(half4v*)(ph + di) = h;
    *(half4v*)(pl + di) = l;
    float s = v.x * v.x + v.y * v.y + v.z * v.z + v.w * v.w;
#pragma unroll
    for (int off = 32; off > 0; off >>= 1) s += __shfl_down(s, off, 64);
    if (lane == 0) c2[row] = s;
}

// ---------------- main kernel ----------------

__global__ void __launch_bounds__(512)
vq_main_fast(const _Float16* __restrict__ xh_g, const _Float16* __restrict__ xl_g,
             const _Float16* __restrict__ ch_p, const _Float16* __restrict__ cl_p,
             const float* __restrict__ c2, float* __restrict__ pd, int* __restrict__ pi) {
    // xh [0,64K), xl [64K,128K); row = 512B = 32 granules of 16B; phys granule
    // p of row r holds logical granule p ^ (r&7).
    __shared__ __align__(16) char lds[131072];

    const int t    = threadIdx.x;
    const int lane = t & 63;
    const int wv   = t >> 6;                 // 8 waves
    const int wy   = wv >> 1, wx = wv & 1;   // 4x2: wave tile 32 rows x 64 cols
    const int fr   = lane & 15;              // row/col within 16x16 tile
    const int g    = lane >> 4;              // k-group 0..3

    const int split = blockIdx.x & (SPLITK - 1);
    const int pbase = (blockIdx.x >> 2) * TM;
    const int kbase = split * KCHUNK;

    // ---- one-time A staging (xh, xl full-D), validated rounds 6/7 ----
    {
        const int p31 = lane & 31, rhalf = lane >> 5;   // 2 rows per gld16
#pragma unroll
        for (int q = 0; q < 8; ++q) {
            const int row = wv * 16 + q * 2 + rhalf;
            const int lg  = p31 ^ (row & 7);            // swizzled source granule
            const size_t go = (size_t)(pbase + row) * ROWB + lg * 16;
            gld16((const char*)xh_g + go, lds +         (wv * 16 + q * 2) * ROWB);
            gld16((const char*)xl_g + go, lds + 65536 + (wv * 16 + q * 2) * ROWB);
        }
    }
    __syncthreads();   // the only barrier before the epilogue

    const int fr7 = fr & 7;
    int abase[2];
#pragma unroll
    for (int i = 0; i < 2; ++i) abase[i] = (wy * 32 + i * 16 + fr) * ROWB;

    float best[8];
    int   bidx[8];
#pragma unroll
    for (int i = 0; i < 8; ++i) { best[i] = 3.4e38f; bidx[i] = 0; }

    for (int kt = 0; kt < NTILES; ++kt) {
        const int ktbase = kbase + kt * TN;
        // packed-B slab base for this wave's 4 groups: jg = (ktbase>>4)+wx*4+j
        const char* bhb = (const char*)ch_p + (size_t)((ktbase >> 4) + wx * 4) * 8192 + lane * 16;
        const char* blb = (const char*)cl_p + (size_t)((ktbase >> 4) + wx * 4) * 8192 + lane * 16;

        f32x4 acch[2][4], accm[2][4];
#pragma unroll
        for (int i = 0; i < 2; ++i)
#pragma unroll
            for (int j = 0; j < 4; ++j) {
                f32x4 z = {0.f, 0.f, 0.f, 0.f};
                acch[i][j] = z; accm[i][j] = z;
            }

#pragma unroll
        for (int dk = 0; dk < 8; ++dk) {          // 8 k-steps of 32 halves
            half8v b1[4], b2[4];
#pragma unroll
            for (int j = 0; j < 4; ++j) {         // coalesced 1KB loads from L2/L1
                b1[j] = *(const half8v*)(bhb + j * 8192 + dk * 1024);
                b2[j] = *(const half8v*)(blb + j * 8192 + dk * 1024);
            }
            const int go = ((dk * 4 + g) ^ fr7) << 4;   // swizzled A granule
            half8v a1[2], a3[2];
#pragma unroll
            for (int i = 0; i < 2; ++i) {
                a1[i] = *(const half8v*)(lds + abase[i] + go);           // xh
                a3[i] = *(const half8v*)(lds + 65536 + abase[i] + go);   // xl*2^11
            }
#pragma unroll
            for (int j = 0; j < 4; ++j)
#pragma unroll
                for (int i = 0; i < 2; ++i) {
                    acch[i][j] = __builtin_amdgcn_mfma_f32_16x16x32_f16(a1[i], b1[j], acch[i][j], 0, 0, 0);
                    accm[i][j] = __builtin_amdgcn_mfma_f32_16x16x32_f16(a1[i], b2[j], accm[i][j], 0, 0, 0);
                    accm[i][j] = __builtin_amdgcn_mfma_f32_16x16x32_f16(a3[i], b1[j], accm[i][j], 0, 0, 0);
                }
        }

        // merge tile into running argmin; ascending j + strict < == np first-min
        // d2 = c2 - 2*acc_h - 2^-10*acc_m
#pragma unroll
        for (int j = 0; j < 4; ++j) {
            const int cg = ktbase + wx * 64 + j * 16 + fr;
            const float c2v = c2[cg];
#pragma unroll
            for (int i = 0; i < 2; ++i)
#pragma unroll
                for (int r = 0; r < 4; ++r) {
                    const float v = fmaf(-2.0f, acch[i][j][r],
                                    fmaf(-9.765625e-4f, accm[i][j][r], c2v));
                    const int s = i * 4 + r;
                    if (v < best[s]) { best[s] = v; bidx[s] = cg; }
                }
        }
    }

    // reduce across the 16 fr-lanes per point row, then the 2 wx wave-columns
    __syncthreads();   // all waves done reading A before LDS reuse
    float* rd = (float*)lds;          // 128 rows x 2 cols
    int*   ri = (int*)lds + 256;
#pragma unroll
    for (int i = 0; i < 2; ++i)
#pragma unroll
        for (int r = 0; r < 4; ++r) {
            float bv = best[i * 4 + r];
            int   bi = bidx[i * 4 + r];
#pragma unroll
            for (int off = 1; off < 16; off <<= 1) {   // flips fr bits only
                const float ov = __shfl_xor(bv, off, 64);
                const int   oi = __shfl_xor(bi, off, 64);
                if (ov < bv || (ov == bv && oi < bi)) { bv = ov; bi = oi; }
            }
            if (fr == 0) {
                const int rowl = wy * 32 + i * 16 + g * 4 + r;
                rd[rowl * 2 + wx] = bv;
                ri[rowl * 2 + wx] = bi;
            }
        }
    __syncthreads();
    if (t < TM) {
        float b0 = rd[t * 2];
        int   i0 = ri[t * 2];
        const float v1 = rd[t * 2 + 1];
        const int   i1 = ri[t * 2 + 1];
        if (v1 < b0 || (v1 == b0 && i1 < i0)) { b0 = v1; i0 = i1; }
        pd[split * N_PTS + pbase + t] = b0;
        pi[split * N_PTS + pbase + t] = i0;
    }
}

// ---------------- combine ----------------

__global__ void __launch_bounds__(256)
vq_combine(const float* __restrict__ pd, const int* __restrict__ pi,
           int* __restrict__ out) {
    const int p = blockIdx.x * 256 + threadIdx.x;
    float bb = pd[p];
    int   bi = pi[p];
#pragma unroll
    for (int s = 1; s < SPLITK; ++s) {
        const float v  = pd[s * N_PTS + p];
        const int   vi = pi[s * N_PTS + p];
        if (v < bb || (v == bb && vi < bi)) { bb = v; bi = vi; }
    }
    out[p] = bi;
}

extern "C" void kernel_launch(void* const* d_in, const int* in_sizes, int n_in,
                              void* d_out, int out_size, void* d_ws, size_t ws_size,
                              hipStream_t stream) {
    const float* x    = (const float*)d_in[0];
    const float* vecs = (const float*)d_in[1];
    int* out = (int*)d_out;
    char* ws = (char*)d_ws;

    _Float16* xh = (_Float16*)(ws + WS_XH);
    _Float16* xl = (_Float16*)(ws + WS_XL);
    _Float16* ch = (_Float16*)(ws + WS_CH);
    _Float16* cl = (_Float16*)(ws + WS_CL);
    float* c2 = (float*)(ws + WS_C2);
    float* pd = (float*)(ws + WS_PD);
    int*   pi = (int*)(ws + WS_PI);

    hipLaunchKernelGGL(split_kernel, dim3(N_PTS * D_DIM / 4 / 256), dim3(256), 0, stream,
                       x, xh, xl);
    hipLaunchKernelGGL(cpack_norm, dim3(K_CB / 4), dim3(256), 0, stream,
                       vecs, ch, cl, c2);
    hipLaunchKernelGGL(vq_main_fast, dim3((N_PTS / TM) * SPLITK), dim3(512), 0, stream,
                       xh, xl, ch, cl, c2, pd, pi);
    hipLaunchKernelGGL(vq_combine, dim3(N_PTS / 256), dim3(256), 0, stream,
                       pd, pi, out);
}